// Round 1
// baseline (662.482 us; speedup 1.0000x reference)
//
#include <hip/hip_runtime.h>
#include <hip/hip_bf16.h>

#define DD 128
#define N_SRC 200000
#define N_MID 50000
#define N_DST 10000
#define E1 800000
#define E2 160000

// ---------------- CSR build kernels ----------------

__global__ void hist_kernel(const int* __restrict__ col, int E, int* __restrict__ rs) {
    int e = blockIdx.x * 256 + threadIdx.x;
    if (e < E) atomicAdd(&rs[col[e] + 1], 1);
}

// single-block inclusive scan, 1024 threads, chunked
__global__ void scan_kernel(int* __restrict__ data, int n) {
    __shared__ int wsums[16];
    __shared__ int carry_s;
    int tid = threadIdx.x;
    int lane = tid & 63, w = tid >> 6;
    if (tid == 0) carry_s = 0;
    __syncthreads();
    for (int base = 0; base < n; base += 1024) {
        int idx = base + tid;
        int v = (idx < n) ? data[idx] : 0;
        int x = v;
        #pragma unroll
        for (int off = 1; off < 64; off <<= 1) {
            int y = __shfl_up(x, off);
            if (lane >= off) x += y;
        }
        if (lane == 63) wsums[w] = x;
        __syncthreads();
        if (w == 0) {
            int s = (lane < 16) ? wsums[lane] : 0;
            #pragma unroll
            for (int off = 1; off < 16; off <<= 1) {
                int y = __shfl_up(s, off);
                if (lane >= off) s += y;
            }
            if (lane < 16) wsums[lane] = s;
        }
        __syncthreads();
        int off = carry_s + (w > 0 ? wsums[w - 1] : 0);
        if (idx < n) data[idx] = x + off;
        int total = wsums[15];
        __syncthreads();
        if (tid == 0) carry_s += total;
        __syncthreads();
    }
}

__global__ void copy_kernel(const int* __restrict__ src, int* __restrict__ dst, int n) {
    int i = blockIdx.x * 256 + threadIdx.x;
    if (i < n) dst[i] = src[i];
}

__global__ void fill_kernel(const int* __restrict__ row, const int* __restrict__ col, int E,
                            int* __restrict__ cursor, int* __restrict__ csr) {
    int e = blockIdx.x * 256 + threadIdx.x;
    if (e < E) {
        int c = col[e];
        int p = atomicAdd(&cursor[c], 1);
        csr[p] = row[e];
    }
}

// Build WT[k][j] = (k<128 ? Wl[j][k] : Wr[j][k-128]), 256x128 row-major
__global__ void prep_wt_kernel(const float* __restrict__ Wl, const float* __restrict__ Wr,
                               float* __restrict__ WT) {
    int idx = blockIdx.x * 256 + threadIdx.x;
    if (idx < 256 * 128) {
        int k = idx >> 7;
        int j = idx & 127;
        WT[idx] = (k < 128) ? Wl[j * 128 + k] : Wr[j * 128 + (k - 128)];
    }
}

// ---------------- fused SAGE layer kernel ----------------
// block = 256 threads, handles 32 dst rows.
// Phase A: wave-per-row mean aggregation (coalesced float2 gather) + x_dst stage -> LDS [32][256]
// Phase B: 4x4 register-tiled GEMV vs WT (256x128), bias, L2-normalize, optional ReLU.

template <bool RELU>
__global__ __launch_bounds__(256) void sage_kernel(
    const float* __restrict__ x_src, const float* __restrict__ x_dst,
    const int* __restrict__ rowstart, const int* __restrict__ csr,
    const float* __restrict__ WT, const float* __restrict__ bias,
    float* __restrict__ out, int n_dst)
{
    __shared__ float sIn[32 * 256];
    const int tid = threadIdx.x;
    const int i0 = blockIdx.x * 32;
    const int lane = tid & 63;
    const int w = tid >> 6;

    // ---- Phase A ----
    for (int q = 0; q < 8; ++q) {
        int r = w * 8 + q;
        int i = i0 + r;
        if (i < n_dst) {
            int e0 = rowstart[i], e1 = rowstart[i + 1];
            float accx = 0.f, accy = 0.f;
            for (int e = e0; e < e1; ++e) {
                int src = csr[e];
                const float2 v = *(const float2*)(x_src + (size_t)src * DD + lane * 2);
                accx += v.x;
                accy += v.y;
            }
            float scale = (e1 > e0) ? 1.f / (float)(e1 - e0) : 0.f;
            sIn[r * 256 + lane * 2]     = accx * scale;
            sIn[r * 256 + lane * 2 + 1] = accy * scale;
            const float2 xd = *(const float2*)(x_dst + (size_t)i * DD + lane * 2);
            sIn[r * 256 + 128 + lane * 2]     = xd.x;
            sIn[r * 256 + 128 + lane * 2 + 1] = xd.y;
        } else {
            sIn[r * 256 + lane * 2] = 0.f;
            sIn[r * 256 + lane * 2 + 1] = 0.f;
            sIn[r * 256 + 128 + lane * 2] = 0.f;
            sIn[r * 256 + 128 + lane * 2 + 1] = 0.f;
        }
    }
    __syncthreads();

    // ---- Phase B ----
    const int ty = tid >> 5;  // 0..7  -> rows ty*4 .. ty*4+3
    const int tx = tid & 31;  // 0..31 -> cols tx*4 .. tx*4+3
    float acc[4][4] = {{0.f}};
    const float4* sIn4 = (const float4*)sIn;
    const float4* WT4 = (const float4*)WT;

    for (int kk = 0; kk < 64; ++kk) {
        float a[4][4];
        #pragma unroll
        for (int r = 0; r < 4; ++r) {
            float4 t = sIn4[(ty * 4 + r) * 64 + kk];
            a[r][0] = t.x; a[r][1] = t.y; a[r][2] = t.z; a[r][3] = t.w;
        }
        #pragma unroll
        for (int m = 0; m < 4; ++m) {
            float4 wv = WT4[(kk * 4 + m) * 32 + tx];
            #pragma unroll
            for (int r = 0; r < 4; ++r) {
                acc[r][0] += a[r][m] * wv.x;
                acc[r][1] += a[r][m] * wv.y;
                acc[r][2] += a[r][m] * wv.z;
                acc[r][3] += a[r][m] * wv.w;
            }
        }
    }

    // ---- epilogue: bias, L2 normalize per row, optional ReLU, store ----
    float4 bv = ((const float4*)bias)[tx];
    float bvals[4] = {bv.x, bv.y, bv.z, bv.w};
    #pragma unroll
    for (int r = 0; r < 4; ++r) {
        float v0 = acc[r][0] + bvals[0];
        float v1 = acc[r][1] + bvals[1];
        float v2 = acc[r][2] + bvals[2];
        float v3 = acc[r][3] + bvals[3];
        float s = v0 * v0 + v1 * v1 + v2 * v2 + v3 * v3;
        #pragma unroll
        for (int off = 1; off < 32; off <<= 1) s += __shfl_xor(s, off);
        float scale = 1.f / fmaxf(sqrtf(s), 1e-12f);
        v0 *= scale; v1 *= scale; v2 *= scale; v3 *= scale;
        if (RELU) {
            v0 = fmaxf(v0, 0.f); v1 = fmaxf(v1, 0.f);
            v2 = fmaxf(v2, 0.f); v3 = fmaxf(v3, 0.f);
        }
        int i = i0 + ty * 4 + r;
        if (i < n_dst) {
            float4 o = make_float4(v0, v1, v2, v3);
            *(float4*)(out + (size_t)i * DD + tx * 4) = o;
        }
    }
}

// ---------------- launcher ----------------

extern "C" void kernel_launch(void* const* d_in, const int* in_sizes, int n_in,
                              void* d_out, int out_size, void* d_ws, size_t ws_size,
                              hipStream_t stream) {
    const float* x    = (const float*)d_in[0];
    const float* Wl1  = (const float*)d_in[1];
    const float* bl1  = (const float*)d_in[2];
    const float* Wr1  = (const float*)d_in[3];
    const float* Wl2  = (const float*)d_in[4];
    const float* bl2  = (const float*)d_in[5];
    const float* Wr2  = (const float*)d_in[6];
    const int* row1   = (const int*)d_in[7];
    const int* col1   = (const int*)d_in[8];
    const int* row2   = (const int*)d_in[9];
    const int* col2   = (const int*)d_in[10];
    float* out = (float*)d_out;

    // workspace carve (16B aligned chunks)
    char* p = (char*)d_ws;
    float* h   = (float*)p; p += (size_t)N_MID * DD * sizeof(float);      // 25.6 MB
    float* WT1 = (float*)p; p += (size_t)256 * 128 * sizeof(float);
    float* WT2 = (float*)p; p += (size_t)256 * 128 * sizeof(float);
    int* rs1   = (int*)p;   p += (size_t)(N_MID + 16) * sizeof(int);
    int* cur1  = (int*)p;   p += (size_t)(N_MID + 16) * sizeof(int);
    int* csr1  = (int*)p;   p += (size_t)E1 * sizeof(int);
    int* rs2   = (int*)p;   p += (size_t)(N_DST + 16) * sizeof(int);
    int* cur2  = (int*)p;   p += (size_t)(N_DST + 16) * sizeof(int);
    int* csr2  = (int*)p;   p += (size_t)E2 * sizeof(int);

    // zero rowstarts (workspace is poisoned before every call)
    hipMemsetAsync(rs1, 0, (N_MID + 1) * sizeof(int), stream);
    hipMemsetAsync(rs2, 0, (N_DST + 1) * sizeof(int), stream);

    // weight transposes
    prep_wt_kernel<<<128, 256, 0, stream>>>(Wl1, Wr1, WT1);
    prep_wt_kernel<<<128, 256, 0, stream>>>(Wl2, Wr2, WT2);

    // CSR layer 1
    hist_kernel<<<E1 / 256, 256, 0, stream>>>(col1, E1, rs1);
    scan_kernel<<<1, 1024, 0, stream>>>(rs1, N_MID + 1);
    copy_kernel<<<(N_MID + 255) / 256, 256, 0, stream>>>(rs1, cur1, N_MID);
    fill_kernel<<<E1 / 256, 256, 0, stream>>>(row1, col1, E1, cur1, csr1);

    // CSR layer 2
    hist_kernel<<<E2 / 256, 256, 0, stream>>>(col2, E2, rs2);
    scan_kernel<<<1, 1024, 0, stream>>>(rs2, N_DST + 1);
    copy_kernel<<<(N_DST + 255) / 256, 256, 0, stream>>>(rs2, cur2, N_DST);
    fill_kernel<<<E2 / 256, 256, 0, stream>>>(row2, col2, E2, cur2, csr2);

    // layer 1: src = x (all), dst = x[:N_MID], ReLU
    sage_kernel<true><<<(N_MID + 31) / 32, 256, 0, stream>>>(
        x, x, rs1, csr1, WT1, bl1, h, N_MID);

    // layer 2: src = h, dst = h[:N_DST], no ReLU
    sage_kernel<false><<<(N_DST + 31) / 32, 256, 0, stream>>>(
        h, h, rs2, csr2, WT2, bl2, out, N_DST);
}

// Round 2
// 438.764 us; speedup vs baseline: 1.5099x; 1.5099x over previous
//
#include <hip/hip_runtime.h>
#include <hip/hip_bf16.h>

#define DD 128
#define N_SRC 200000
#define N_MID 50000
#define N_DST 10000
#define E1 800000
#define E2 160000

// ---------------- helpers ----------------

__device__ __forceinline__ int wave_incl_scan(int x, int lane) {
    #pragma unroll
    for (int off = 1; off < 64; off <<= 1) {
        int y = __shfl_up(x, off);
        if (lane >= off) x += y;
    }
    return x;
}

// ---------------- CSR build kernels (fused across both layers) ----------------

__global__ void zero_kernel(int* __restrict__ rs1, int* __restrict__ rs2) {
    int i = blockIdx.x * 256 + threadIdx.x;
    if (i < N_MID + 1) rs1[i] = 0;
    if (i < N_DST + 1) rs2[i] = 0;
}

__global__ void hist_both(const int* __restrict__ col1, const int* __restrict__ col2,
                          int* __restrict__ rs1, int* __restrict__ rs2) {
    int e = blockIdx.x * 256 + threadIdx.x;
    if (e < E1) atomicAdd(&rs1[col1[e] + 1], 1);
    else if (e < E1 + E2) atomicAdd(&rs2[col2[e - E1] + 1], 1);
}

// per-1024-chunk inclusive scan; chunk totals -> bsums[b]
__global__ __launch_bounds__(1024) void scan_partial(int* __restrict__ rs1, int n1,
                                                     int* __restrict__ rs2, int n2,
                                                     int* __restrict__ bsums, int nb1) {
    __shared__ int wsums[16];
    int b = blockIdx.x;
    int* data = (b < nb1) ? rs1 : rs2;
    int n     = (b < nb1) ? n1 : n2;
    int boff  = (b < nb1) ? b : b - nb1;
    int tid = threadIdx.x, lane = tid & 63, w = tid >> 6;
    int idx = boff * 1024 + tid;
    int v = (idx < n) ? data[idx] : 0;
    int x = wave_incl_scan(v, lane);
    if (lane == 63) wsums[w] = x;
    __syncthreads();
    if (w == 0) {
        int s = (lane < 16) ? wsums[lane] : 0;
        s = wave_incl_scan(s, lane);
        if (lane < 16) wsums[lane] = s;
    }
    __syncthreads();
    if (w > 0) x += wsums[w - 1];
    if (idx < n) data[idx] = x;
    if (tid == 1023) bsums[b] = x;  // padded lanes contribute 0 -> x == chunk total
}

// single 64-thread block: inclusive scan of the two bsum segments
__global__ void scan_sums(int* __restrict__ bsums, int nb1, int nb2) {
    int lane = threadIdx.x & 63;
    int v1 = (lane < nb1) ? bsums[lane] : 0;
    int x1 = wave_incl_scan(v1, lane);
    int v2 = (lane < nb2) ? bsums[nb1 + lane] : 0;
    int x2 = wave_incl_scan(v2, lane);
    if (lane < nb1) bsums[lane] = x1;
    if (lane < nb2) bsums[nb1 + lane] = x2;
}

// add chunk offsets; also write cursor = rowstart (fuses the old copy_kernel)
__global__ __launch_bounds__(1024) void scan_add(int* __restrict__ rs1, int n1, int* __restrict__ cur1,
                                                 int* __restrict__ rs2, int n2, int* __restrict__ cur2,
                                                 const int* __restrict__ bsums, int nb1) {
    int b = blockIdx.x;
    int* data = (b < nb1) ? rs1 : rs2;
    int* cur  = (b < nb1) ? cur1 : cur2;
    int n     = (b < nb1) ? n1 : n2;
    int boff  = (b < nb1) ? b : b - nb1;
    int idx = boff * 1024 + threadIdx.x;
    int off = (boff > 0) ? bsums[b - 1] : 0;
    if (idx < n) {
        int v = data[idx] + off;
        data[idx] = v;
        if (idx < n - 1) cur[idx] = v;
    }
}

__global__ void fill_both(const int* __restrict__ row1, const int* __restrict__ col1,
                          const int* __restrict__ row2, const int* __restrict__ col2,
                          int* __restrict__ cur1, int* __restrict__ cur2,
                          int* __restrict__ csr1, int* __restrict__ csr2) {
    int e = blockIdx.x * 256 + threadIdx.x;
    if (e < E1) {
        int p = atomicAdd(&cur1[col1[e]], 1);
        csr1[p] = row1[e];
    } else if (e < E1 + E2) {
        int e2 = e - E1;
        int p = atomicAdd(&cur2[col2[e2]], 1);
        csr2[p] = row2[e2];
    }
}

// Build WT[k][j] = (k<128 ? Wl[j][k] : Wr[j][k-128]) for both layers
__global__ void prep_wt_both(const float* __restrict__ Wl1, const float* __restrict__ Wr1,
                             float* __restrict__ WT1,
                             const float* __restrict__ Wl2, const float* __restrict__ Wr2,
                             float* __restrict__ WT2) {
    int idx = blockIdx.x * 256 + threadIdx.x;
    const int half = 256 * 128;
    const float* Wl; const float* Wr; float* WT; int id;
    if (idx < half) { Wl = Wl1; Wr = Wr1; WT = WT1; id = idx; }
    else            { Wl = Wl2; Wr = Wr2; WT = WT2; id = idx - half; }
    int k = id >> 7, j = id & 127;
    WT[id] = (k < 128) ? Wl[j * 128 + k] : Wr[j * 128 + (k - 128)];
}

// ---------------- fused SAGE layer kernel ----------------
// block = 256 threads, ROWS dst rows per block.
// Phase A: wave-per-row mean aggregation, 8-way unrolled masked gather (8 loads in flight)
// Phase B: register-tiled GEMV vs WT (256x128), bias, L2-normalize, optional ReLU.

template <int ROWS, bool RELU>
__global__ __launch_bounds__(256) void sage_kernel(
    const float* __restrict__ x_src, const float* __restrict__ x_dst,
    const int* __restrict__ rowstart, const int* __restrict__ csr,
    const float* __restrict__ WT, const float* __restrict__ bias,
    float* __restrict__ out, int n_dst)
{
    __shared__ float sIn[ROWS * 256];
    const int tid = threadIdx.x;
    const int i0 = blockIdx.x * ROWS;
    const int lane = tid & 63;
    const int w = tid >> 6;
    constexpr int RPW = ROWS / 4;   // rows per wave

    // ---- Phase A: mean-aggregate + stage x_dst ----
    for (int q = 0; q < RPW; ++q) {
        int r = w * RPW + q;
        int i = i0 + r;
        float outx = 0.f, outy = 0.f, dx = 0.f, dy = 0.f;
        if (i < n_dst) {
            int e0 = rowstart[i], e1 = rowstart[i + 1];
            int deg = e1 - e0;
            if (deg > 0) {
                float accx = 0.f, accy = 0.f;
                int e1m1 = e1 - 1;
                for (int e = e0; e < e1; e += 8) {
                    int idxv[8]; float m[8];
                    #pragma unroll
                    for (int j = 0; j < 8; ++j) {
                        int ee = e + j;
                        idxv[j] = csr[ee < e1 ? ee : e1m1];
                        m[j] = (ee < e1) ? 1.f : 0.f;
                    }
                    float2 v[8];
                    #pragma unroll
                    for (int j = 0; j < 8; ++j)
                        v[j] = *(const float2*)(x_src + (size_t)idxv[j] * DD + lane * 2);
                    #pragma unroll
                    for (int j = 0; j < 8; ++j) {
                        accx += v[j].x * m[j];
                        accy += v[j].y * m[j];
                    }
                }
                float s = 1.f / (float)deg;
                outx = accx * s;
                outy = accy * s;
            }
            const float2 xd = *(const float2*)(x_dst + (size_t)i * DD + lane * 2);
            dx = xd.x; dy = xd.y;
        }
        sIn[r * 256 + lane * 2]           = outx;
        sIn[r * 256 + lane * 2 + 1]       = outy;
        sIn[r * 256 + 128 + lane * 2]     = dx;
        sIn[r * 256 + 128 + lane * 2 + 1] = dy;
    }
    __syncthreads();

    // ---- Phase B: [ROWS,256] @ WT[256,128] ----
    constexpr int R = ROWS / 8;     // rows per thread
    const int ty = tid >> 5;        // 0..7
    const int tx = tid & 31;        // 0..31 -> cols tx*4..tx*4+3
    float acc[R][4];
    #pragma unroll
    for (int r = 0; r < R; ++r) { acc[r][0] = acc[r][1] = acc[r][2] = acc[r][3] = 0.f; }
    const float4* sIn4 = (const float4*)sIn;
    const float4* WT4 = (const float4*)WT;

    for (int kk = 0; kk < 64; ++kk) {
        float a[R][4];
        #pragma unroll
        for (int r = 0; r < R; ++r) {
            float4 t = sIn4[(ty * R + r) * 64 + kk];
            a[r][0] = t.x; a[r][1] = t.y; a[r][2] = t.z; a[r][3] = t.w;
        }
        #pragma unroll
        for (int m = 0; m < 4; ++m) {
            float4 wv = WT4[(kk * 4 + m) * 32 + tx];
            #pragma unroll
            for (int r = 0; r < R; ++r) {
                acc[r][0] += a[r][m] * wv.x;
                acc[r][1] += a[r][m] * wv.y;
                acc[r][2] += a[r][m] * wv.z;
                acc[r][3] += a[r][m] * wv.w;
            }
        }
    }

    // ---- epilogue: bias, L2 normalize, optional ReLU, store ----
    float4 bv = ((const float4*)bias)[tx];
    #pragma unroll
    for (int r = 0; r < R; ++r) {
        float v0 = acc[r][0] + bv.x;
        float v1 = acc[r][1] + bv.y;
        float v2 = acc[r][2] + bv.z;
        float v3 = acc[r][3] + bv.w;
        float s = v0 * v0 + v1 * v1 + v2 * v2 + v3 * v3;
        #pragma unroll
        for (int off = 1; off < 32; off <<= 1) s += __shfl_xor(s, off);
        float scale = 1.f / fmaxf(sqrtf(s), 1e-12f);
        v0 *= scale; v1 *= scale; v2 *= scale; v3 *= scale;
        if (RELU) {
            v0 = fmaxf(v0, 0.f); v1 = fmaxf(v1, 0.f);
            v2 = fmaxf(v2, 0.f); v3 = fmaxf(v3, 0.f);
        }
        int i = i0 + ty * R + r;
        if (i < n_dst) {
            *(float4*)(out + (size_t)i * DD + tx * 4) = make_float4(v0, v1, v2, v3);
        }
    }
}

// ---------------- launcher ----------------

extern "C" void kernel_launch(void* const* d_in, const int* in_sizes, int n_in,
                              void* d_out, int out_size, void* d_ws, size_t ws_size,
                              hipStream_t stream) {
    const float* x    = (const float*)d_in[0];
    const float* Wl1  = (const float*)d_in[1];
    const float* bl1  = (const float*)d_in[2];
    const float* Wr1  = (const float*)d_in[3];
    const float* Wl2  = (const float*)d_in[4];
    const float* bl2  = (const float*)d_in[5];
    const float* Wr2  = (const float*)d_in[6];
    const int* row1   = (const int*)d_in[7];
    const int* col1   = (const int*)d_in[8];
    const int* row2   = (const int*)d_in[9];
    const int* col2   = (const int*)d_in[10];
    float* out = (float*)d_out;

    // workspace carve (16B aligned chunks)
    char* p = (char*)d_ws;
    float* h   = (float*)p; p += (size_t)N_MID * DD * sizeof(float);      // 25.6 MB
    float* WT1 = (float*)p; p += (size_t)256 * 128 * sizeof(float);
    float* WT2 = (float*)p; p += (size_t)256 * 128 * sizeof(float);
    int* rs1   = (int*)p;   p += (size_t)(N_MID + 16) * sizeof(int);
    int* cur1  = (int*)p;   p += (size_t)(N_MID + 16) * sizeof(int);
    int* csr1  = (int*)p;   p += (size_t)E1 * sizeof(int);
    int* rs2   = (int*)p;   p += (size_t)(N_DST + 16) * sizeof(int);
    int* cur2  = (int*)p;   p += (size_t)(N_DST + 16) * sizeof(int);
    int* csr2  = (int*)p;   p += (size_t)E2 * sizeof(int);
    int* bsums = (int*)p;   p += 64 * sizeof(int);

    const int n1 = N_MID + 1, n2 = N_DST + 1;
    const int nb1 = (n1 + 1023) / 1024;   // 49
    const int nb2 = (n2 + 1023) / 1024;   // 10

    zero_kernel<<<(N_MID + 1 + 255) / 256, 256, 0, stream>>>(rs1, rs2);
    prep_wt_both<<<256, 256, 0, stream>>>(Wl1, Wr1, WT1, Wl2, Wr2, WT2);
    hist_both<<<(E1 + E2 + 255) / 256, 256, 0, stream>>>(col1, col2, rs1, rs2);
    scan_partial<<<nb1 + nb2, 1024, 0, stream>>>(rs1, n1, rs2, n2, bsums, nb1);
    scan_sums<<<1, 64, 0, stream>>>(bsums, nb1, nb2);
    scan_add<<<nb1 + nb2, 1024, 0, stream>>>(rs1, n1, cur1, rs2, n2, cur2, bsums, nb1);
    fill_both<<<(E1 + E2 + 255) / 256, 256, 0, stream>>>(row1, col1, row2, col2,
                                                         cur1, cur2, csr1, csr2);

    // layer 1: src = x (all), dst = x[:N_MID], ReLU
    sage_kernel<32, true><<<(N_MID + 31) / 32, 256, 0, stream>>>(
        x, x, rs1, csr1, WT1, bl1, h, N_MID);

    // layer 2: src = h, dst = h[:N_DST], no ReLU
    sage_kernel<16, false><<<(N_DST + 15) / 16, 256, 0, stream>>>(
        h, h, rs2, csr2, WT2, bl2, out, N_DST);
}

// Round 3
// 403.930 us; speedup vs baseline: 1.6401x; 1.0862x over previous
//
#include <hip/hip_runtime.h>
#include <hip/hip_bf16.h>

#define DD 128
#define N_SRC 200000
#define N_MID 50000
#define N_DST 10000
#define E1 800000
#define E2 160000

// ---------------- helpers ----------------

__device__ __forceinline__ int wave_incl_scan(int x, int lane) {
    #pragma unroll
    for (int off = 1; off < 64; off <<= 1) {
        int y = __shfl_up(x, off);
        if (lane >= off) x += y;
    }
    return x;
}

// ---------------- CSR build kernels (fused across both layers) ----------------

__global__ void zero_kernel(int* __restrict__ rs1, int* __restrict__ rs2) {
    int i = blockIdx.x * 256 + threadIdx.x;
    if (i < N_MID + 1) rs1[i] = 0;
    if (i < N_DST + 1) rs2[i] = 0;
}

__global__ void hist_both(const int* __restrict__ col1, const int* __restrict__ col2,
                          int* __restrict__ rs1, int* __restrict__ rs2) {
    int e = blockIdx.x * 256 + threadIdx.x;
    if (e < E1) atomicAdd(&rs1[col1[e] + 1], 1);
    else if (e < E1 + E2) atomicAdd(&rs2[col2[e - E1] + 1], 1);
}

// per-1024-chunk inclusive scan; chunk totals -> bsums[b]
__global__ __launch_bounds__(1024) void scan_partial(int* __restrict__ rs1, int n1,
                                                     int* __restrict__ rs2, int n2,
                                                     int* __restrict__ bsums, int nb1) {
    __shared__ int wsums[16];
    int b = blockIdx.x;
    int* data = (b < nb1) ? rs1 : rs2;
    int n     = (b < nb1) ? n1 : n2;
    int boff  = (b < nb1) ? b : b - nb1;
    int tid = threadIdx.x, lane = tid & 63, w = tid >> 6;
    int idx = boff * 1024 + tid;
    int v = (idx < n) ? data[idx] : 0;
    int x = wave_incl_scan(v, lane);
    if (lane == 63) wsums[w] = x;
    __syncthreads();
    if (w == 0) {
        int s = (lane < 16) ? wsums[lane] : 0;
        s = wave_incl_scan(s, lane);
        if (lane < 16) wsums[lane] = s;
    }
    __syncthreads();
    if (w > 0) x += wsums[w - 1];
    if (idx < n) data[idx] = x;
    if (tid == 1023) bsums[b] = x;
}

// single 64-thread block: inclusive scan of the two bsum segments
__global__ void scan_sums(int* __restrict__ bsums, int nb1, int nb2) {
    int lane = threadIdx.x & 63;
    int v1 = (lane < nb1) ? bsums[lane] : 0;
    int x1 = wave_incl_scan(v1, lane);
    int v2 = (lane < nb2) ? bsums[nb1 + lane] : 0;
    int x2 = wave_incl_scan(v2, lane);
    if (lane < nb1) bsums[lane] = x1;
    if (lane < nb2) bsums[nb1 + lane] = x2;
}

// add chunk offsets; also write cursor = rowstart
__global__ __launch_bounds__(1024) void scan_add(int* __restrict__ rs1, int n1, int* __restrict__ cur1,
                                                 int* __restrict__ rs2, int n2, int* __restrict__ cur2,
                                                 const int* __restrict__ bsums, int nb1) {
    int b = blockIdx.x;
    int* data = (b < nb1) ? rs1 : rs2;
    int* cur  = (b < nb1) ? cur1 : cur2;
    int n     = (b < nb1) ? n1 : n2;
    int boff  = (b < nb1) ? b : b - nb1;
    int idx = boff * 1024 + threadIdx.x;
    int off = (boff > 0) ? bsums[b - 1] : 0;
    if (idx < n) {
        int v = data[idx] + off;
        data[idx] = v;
        if (idx < n - 1) cur[idx] = v;
    }
}

__global__ void fill_both(const int* __restrict__ row1, const int* __restrict__ col1,
                          const int* __restrict__ row2, const int* __restrict__ col2,
                          int* __restrict__ cur1, int* __restrict__ cur2,
                          int* __restrict__ csr1, int* __restrict__ csr2) {
    int e = blockIdx.x * 256 + threadIdx.x;
    if (e < E1) {
        int p = atomicAdd(&cur1[col1[e]], 1);
        csr1[p] = row1[e];
    } else if (e < E1 + E2) {
        int e2 = e - E1;
        int p = atomicAdd(&cur2[col2[e2]], 1);
        csr2[p] = row2[e2];
    }
}

// Build WT[k][j] = (k<128 ? Wl[j][k] : Wr[j][k-128]) for both layers
__global__ void prep_wt_both(const float* __restrict__ Wl1, const float* __restrict__ Wr1,
                             float* __restrict__ WT1,
                             const float* __restrict__ Wl2, const float* __restrict__ Wr2,
                             float* __restrict__ WT2) {
    int idx = blockIdx.x * 256 + threadIdx.x;
    const int half = 256 * 128;
    const float* Wl; const float* Wr; float* WT; int id;
    if (idx < half) { Wl = Wl1; Wr = Wr1; WT = WT1; id = idx; }
    else            { Wl = Wl2; Wr = Wr2; WT = WT2; id = idx - half; }
    int k = id >> 7, j = id & 127;
    WT[id] = (k < 128) ? Wl[j * 128 + k] : Wr[j * 128 + (k - 128)];
}

// ---------------- fused SAGE layer kernel ----------------
// Phase A: wave-per-row mean aggregation. float4 gather, TWO edges per
// instruction (lanes 0-31 = edge 2j, lanes 32-63 = edge 2j+1). Indices
// fetched coalesced (csr[base+lane]) and distributed via __shfl — no scalar
// dependent chain. Cross-half reduce via shfl_xor(32).
// Phase B: register-tiled GEMV vs WT (256x128), bias, L2-normalize, ReLU.

template <int ROWS, bool RELU>
__global__ __launch_bounds__(256, 5) void sage_kernel(
    const float* __restrict__ x_src, const float* __restrict__ x_dst,
    const int* __restrict__ rowstart, const int* __restrict__ csr,
    const float* __restrict__ WT, const float* __restrict__ bias,
    float* __restrict__ out, int n_dst)
{
    __shared__ float sIn[ROWS * 256];
    const int tid = threadIdx.x;
    const int i0 = blockIdx.x * ROWS;
    const int lane = tid & 63;
    const int w = tid >> 6;
    const int half = lane >> 5;     // 0: even edges / agg store; 1: odd edges / x_dst store
    const int l32 = lane & 31;
    constexpr int RPW = ROWS / 4;

    const float4* __restrict__ x4 = (const float4*)x_src;
    const float4* __restrict__ xd4 = (const float4*)x_dst;

    // ---- Phase A ----
    for (int q = 0; q < RPW; ++q) {
        int r = w * RPW + q;
        int i = i0 + r;
        float4* sRow = (float4*)&sIn[r * 256];
        if (i < n_dst) {
            int e0 = rowstart[i], e1 = rowstart[i + 1];
            int deg = e1 - e0;
            float ax = 0.f, ay = 0.f, az = 0.f, aw = 0.f;
            for (int base = e0; base < e1; base += 64) {
                int li = base + lane;
                int iv = csr[li < e1 ? li : e1 - 1];   // coalesced index fetch
                int nb = e1 - base; if (nb > 64) nb = 64;
                for (int g = 0; g < nb; g += 16) {
                    int idx[8]; float m[8];
                    #pragma unroll
                    for (int j = 0; j < 8; ++j) {
                        int rel = g + 2 * j + half;    // edge slot within chunk
                        idx[j] = __shfl(iv, rel < 63 ? rel : 63);
                        m[j] = (base + rel < e1) ? 1.f : 0.f;
                    }
                    float4 v[8];
                    #pragma unroll
                    for (int j = 0; j < 8; ++j)
                        v[j] = x4[(size_t)idx[j] * 32 + l32];
                    #pragma unroll
                    for (int j = 0; j < 8; ++j) {
                        ax += v[j].x * m[j];
                        ay += v[j].y * m[j];
                        az += v[j].z * m[j];
                        aw += v[j].w * m[j];
                    }
                }
            }
            // combine even/odd halves: lane l and l^32 hold partials of same features
            ax += __shfl_xor(ax, 32);
            ay += __shfl_xor(ay, 32);
            az += __shfl_xor(az, 32);
            aw += __shfl_xor(aw, 32);
            float s = (deg > 0) ? 1.f / (float)deg : 0.f;
            float4 xd = xd4[(size_t)i * 32 + l32];
            if (half == 0) {
                sRow[l32] = make_float4(ax * s, ay * s, az * s, aw * s);
            } else {
                sRow[32 + l32] = xd;
            }
        } else {
            sRow[(half ? 32 : 0) + l32] = make_float4(0.f, 0.f, 0.f, 0.f);
        }
    }
    __syncthreads();

    // ---- Phase B: [ROWS,256] @ WT[256,128] ----
    constexpr int R = ROWS / 8;
    const int ty = tid >> 5;
    const int tx = tid & 31;
    float acc[R][4];
    #pragma unroll
    for (int r = 0; r < R; ++r) { acc[r][0] = acc[r][1] = acc[r][2] = acc[r][3] = 0.f; }
    const float4* sIn4 = (const float4*)sIn;
    const float4* WT4 = (const float4*)WT;

    for (int kk = 0; kk < 64; ++kk) {
        float a[R][4];
        #pragma unroll
        for (int r = 0; r < R; ++r) {
            float4 t = sIn4[(ty * R + r) * 64 + kk];
            a[r][0] = t.x; a[r][1] = t.y; a[r][2] = t.z; a[r][3] = t.w;
        }
        #pragma unroll
        for (int m = 0; m < 4; ++m) {
            float4 wv = WT4[(kk * 4 + m) * 32 + tx];
            #pragma unroll
            for (int r = 0; r < R; ++r) {
                acc[r][0] += a[r][m] * wv.x;
                acc[r][1] += a[r][m] * wv.y;
                acc[r][2] += a[r][m] * wv.z;
                acc[r][3] += a[r][m] * wv.w;
            }
        }
    }

    // ---- epilogue ----
    float4 bv = ((const float4*)bias)[tx];
    #pragma unroll
    for (int r = 0; r < R; ++r) {
        float v0 = acc[r][0] + bv.x;
        float v1 = acc[r][1] + bv.y;
        float v2 = acc[r][2] + bv.z;
        float v3 = acc[r][3] + bv.w;
        float s = v0 * v0 + v1 * v1 + v2 * v2 + v3 * v3;
        #pragma unroll
        for (int off = 1; off < 32; off <<= 1) s += __shfl_xor(s, off);
        float scale = 1.f / fmaxf(sqrtf(s), 1e-12f);
        v0 *= scale; v1 *= scale; v2 *= scale; v3 *= scale;
        if (RELU) {
            v0 = fmaxf(v0, 0.f); v1 = fmaxf(v1, 0.f);
            v2 = fmaxf(v2, 0.f); v3 = fmaxf(v3, 0.f);
        }
        int i = i0 + ty * R + r;
        if (i < n_dst) {
            *(float4*)(out + (size_t)i * DD + tx * 4) = make_float4(v0, v1, v2, v3);
        }
    }
}

// ---------------- launcher ----------------

extern "C" void kernel_launch(void* const* d_in, const int* in_sizes, int n_in,
                              void* d_out, int out_size, void* d_ws, size_t ws_size,
                              hipStream_t stream) {
    const float* x    = (const float*)d_in[0];
    const float* Wl1  = (const float*)d_in[1];
    const float* bl1  = (const float*)d_in[2];
    const float* Wr1  = (const float*)d_in[3];
    const float* Wl2  = (const float*)d_in[4];
    const float* bl2  = (const float*)d_in[5];
    const float* Wr2  = (const float*)d_in[6];
    const int* row1   = (const int*)d_in[7];
    const int* col1   = (const int*)d_in[8];
    const int* row2   = (const int*)d_in[9];
    const int* col2   = (const int*)d_in[10];
    float* out = (float*)d_out;

    char* p = (char*)d_ws;
    float* h   = (float*)p; p += (size_t)N_MID * DD * sizeof(float);
    float* WT1 = (float*)p; p += (size_t)256 * 128 * sizeof(float);
    float* WT2 = (float*)p; p += (size_t)256 * 128 * sizeof(float);
    int* rs1   = (int*)p;   p += (size_t)(N_MID + 16) * sizeof(int);
    int* cur1  = (int*)p;   p += (size_t)(N_MID + 16) * sizeof(int);
    int* csr1  = (int*)p;   p += (size_t)E1 * sizeof(int);
    int* rs2   = (int*)p;   p += (size_t)(N_DST + 16) * sizeof(int);
    int* cur2  = (int*)p;   p += (size_t)(N_DST + 16) * sizeof(int);
    int* csr2  = (int*)p;   p += (size_t)E2 * sizeof(int);
    int* bsums = (int*)p;   p += 64 * sizeof(int);

    const int n1 = N_MID + 1, n2 = N_DST + 1;
    const int nb1 = (n1 + 1023) / 1024;   // 49
    const int nb2 = (n2 + 1023) / 1024;   // 10

    zero_kernel<<<(N_MID + 1 + 255) / 256, 256, 0, stream>>>(rs1, rs2);
    prep_wt_both<<<256, 256, 0, stream>>>(Wl1, Wr1, WT1, Wl2, Wr2, WT2);
    hist_both<<<(E1 + E2 + 255) / 256, 256, 0, stream>>>(col1, col2, rs1, rs2);
    scan_partial<<<nb1 + nb2, 1024, 0, stream>>>(rs1, n1, rs2, n2, bsums, nb1);
    scan_sums<<<1, 64, 0, stream>>>(bsums, nb1, nb2);
    scan_add<<<nb1 + nb2, 1024, 0, stream>>>(rs1, n1, cur1, rs2, n2, cur2, bsums, nb1);
    fill_both<<<(E1 + E2 + 255) / 256, 256, 0, stream>>>(row1, col1, row2, col2,
                                                         cur1, cur2, csr1, csr2);

    sage_kernel<32, true><<<(N_MID + 31) / 32, 256, 0, stream>>>(
        x, x, rs1, csr1, WT1, bl1, h, N_MID);

    sage_kernel<16, false><<<(N_DST + 15) / 16, 256, 0, stream>>>(
        h, h, rs2, csr2, WT2, bl2, out, N_DST);
}